// Round 1
// baseline (202.043 us; speedup 1.0000x reference)
//
#include <hip/hip_runtime.h>
#include <stdint.h>

#define B_TOT 16384
#define IN_DIM 128
#define H1 256
#define H2 128
#define NC 10

// ---------------------------------------------------------------------------
// Kernel A: cur1[b][n] = sum_k x[b][k] * W1[n][k]  (+ b1[n] added at the end)
// grid = B/16 blocks of 256 threads; each block: 16 rows x 256 outputs.
// x tile (16x128, contiguous 8KB) staged in LDS; W1 rows read from L2.
// ---------------------------------------------------------------------------
__global__ __launch_bounds__(256) void gemm1_kernel(
    const float* __restrict__ x, const float* __restrict__ W1,
    const float* __restrict__ b1, float* __restrict__ cur1) {
  __shared__ float xs[16 * 128];
  const int tid = threadIdx.x;
  const long row0 = (long)blockIdx.x * 16;

  // contiguous 16x128 tile copy, fully coalesced (512 float4 / 256 threads)
  const float4* xt = (const float4*)(x + row0 * IN_DIM);
  float4* xs4 = (float4*)xs;
  xs4[tid] = xt[tid];
  xs4[tid + 256] = xt[tid + 256];
  __syncthreads();

  const int n = tid;  // output neuron
  float acc[16];
#pragma unroll
  for (int r = 0; r < 16; ++r) acc[r] = 0.f;

  const float* wrow = W1 + n * IN_DIM;
  for (int k0 = 0; k0 < IN_DIM; k0 += 4) {
    const float4 wv = *(const float4*)(wrow + k0);
#pragma unroll
    for (int r = 0; r < 16; ++r) {
      const float4 xv = *(const float4*)(xs + r * IN_DIM + k0);
      acc[r] = fmaf(wv.x, xv.x, acc[r]);
      acc[r] = fmaf(wv.y, xv.y, acc[r]);
      acc[r] = fmaf(wv.z, xv.z, acc[r]);
      acc[r] = fmaf(wv.w, xv.w, acc[r]);
    }
  }
  const float bias = b1[n];
#pragma unroll
  for (int r = 0; r < 16; ++r)
    cur1[(row0 + r) * H1 + n] = acc[r] + bias;  // bias after dot, like the ref
}

// ---------------------------------------------------------------------------
// Kernel B: fused 20-step recurrent SNN. One wave (64 lanes) per batch row.
//   lane l owns L1 neurons {l, 64+l, 128+l, 192+l}  (mem in 4 VGPRs)
//   lane l owns L2 neurons {2l, 2l+1}               (mem in 2 VGPRs)
//   lanes 0..9 own the 10 output neurons
// Spike vectors live as wave-uniform 64-bit ballot masks; cur2/curo are
// computed by iterating only set bits (scalar s_ff1 loop) and summing
// fp32 weight rows from LDS.
// LDS: W2T [256][128] fp32 (131KB) + WoT [128][10] fp32 (5KB) = 133KB.
// ---------------------------------------------------------------------------
__global__ __launch_bounds__(1024) void snn_kernel(
    const float* __restrict__ cur1,  // may be nullptr -> on-the-fly fallback
    const float* __restrict__ x, const float* __restrict__ W1,
    const float* __restrict__ b1, const float* __restrict__ W2,
    const float* __restrict__ b2, const float* __restrict__ Wo,
    const float* __restrict__ bo, const int* __restrict__ nsp,
    float* __restrict__ out) {
  extern __shared__ float lds[];
  float* w2t = lds;             // [in=256][out=128]
  float* wot = lds + H1 * H2;   // [in=128][out=10]

  const int tid = threadIdx.x;
  // stage W2 transposed (coalesced global read; LDS write conflicts are a
  // one-time ~1us cost per block)
  for (int idx = tid; idx < H2 * H1; idx += 1024) {
    const int o = idx >> 8;      // /256
    const int j = idx & 255;
    w2t[j * H2 + o] = W2[idx];
  }
  for (int idx = tid; idx < NC * H2; idx += 1024) {
    const int o = idx >> 7;      // /128
    const int j = idx & 127;
    wot[j * NC + o] = Wo[idx];
  }
  __syncthreads();

  const int w = tid >> 6;
  const int l = tid & 63;
  const long b = (long)blockIdx.x * 16 + w;

  // --- layer-1 input current (time-invariant) ---
  float c[4];
  if (cur1 != nullptr) {
#pragma unroll
    for (int i = 0; i < 4; ++i) c[i] = cur1[b * H1 + i * 64 + l];
  } else {
    // fallback path if d_ws was too small: compute from x/W1 (L2-served)
    const float* xr = x + b * IN_DIM;
#pragma unroll
    for (int i = 0; i < 4; ++i) {
      const int n = i * 64 + l;
      const float* wr = W1 + n * IN_DIM;
      float a = 0.f;
      for (int k = 0; k < IN_DIM; k += 4) {
        const float4 wv = *(const float4*)(wr + k);
        const float4 xv = *(const float4*)(xr + k);
        a = fmaf(wv.x, xv.x, a);
        a = fmaf(wv.y, xv.y, a);
        a = fmaf(wv.z, xv.z, a);
        a = fmaf(wv.w, xv.w, a);
      }
      c[i] = a + b1[n];
    }
  }

  const int lo = (l < NC) ? l : 0;  // clamp so idle lanes read a safe address
  const float bb0 = b2[2 * l];
  const float bb1 = b2[2 * l + 1];
  const float bol = bo[lo];

  float m1[4] = {0.f, 0.f, 0.f, 0.f};
  float sp1[4] = {0.f, 0.f, 0.f, 0.f};
  float m2a = 0.f, m2b = 0.f, sp2a = 0.f, sp2b = 0.f;
  float mo = 0.f, spo = 0.f, cnt = 0.f;

  const float* w2l = w2t + 2 * l;  // this lane's output pair within a row
  const int nsteps = *nsp;

  for (int t = 0; t < nsteps; ++t) {
    // ---- layer 1 LIF: mem = 0.5*mem + cur - prev_spike; spike = mem > 1 ----
    unsigned long long mk[4];
#pragma unroll
    for (int i = 0; i < 4; ++i) {
      m1[i] = fmaf(0.5f, m1[i], c[i]) - sp1[i];
      const bool s = m1[i] > 1.0f;
      mk[i] = __ballot(s);
      sp1[i] = s ? 1.0f : 0.0f;
    }

    // ---- cur2 = s1 @ W2^T (+ b2 last): iterate set bits only ----
    float a0 = 0.f, a1 = 0.f;
#pragma unroll
    for (int i = 0; i < 4; ++i) {
      unsigned long long m = mk[i];
      const float* base = w2l + (i * 64) * H2;
      while (m) {
        const int j = __builtin_ctzll(m);
        m &= m - 1;
        const float2 wv = *(const float2*)(base + j * H2);
        a0 += wv.x;
        a1 += wv.y;
      }
    }
    a0 += bb0;
    a1 += bb1;

    // ---- layer 2 LIF ----
    m2a = fmaf(0.5f, m2a, a0) - sp2a;
    m2b = fmaf(0.5f, m2b, a1) - sp2b;
    const bool sa = m2a > 1.0f;
    const bool sb = m2b > 1.0f;
    unsigned long long mA = __ballot(sa);
    unsigned long long mB = __ballot(sb);
    sp2a = sa ? 1.0f : 0.0f;
    sp2b = sb ? 1.0f : 0.0f;

    // ---- output layer: curo[o] = sum_j s2[j]*Wo[o][j] (+ bo last) ----
    float co = 0.f;
    while (mA) {  // mask bit j -> neuron 2j
      const int j = __builtin_ctzll(mA);
      mA &= mA - 1;
      co += wot[(2 * j) * NC + lo];
    }
    while (mB) {  // mask bit j -> neuron 2j+1
      const int j = __builtin_ctzll(mB);
      mB &= mB - 1;
      co += wot[(2 * j + 1) * NC + lo];
    }
    co += bol;

    // ---- output LIF + spike count ----
    mo = fmaf(0.5f, mo, co) - spo;
    const bool so = mo > 1.0f;
    spo = so ? 1.0f : 0.0f;
    cnt += spo;
  }

  if (l < NC) out[b * NC + l] = cnt;
}

// ---------------------------------------------------------------------------
extern "C" void kernel_launch(void* const* d_in, const int* in_sizes, int n_in,
                              void* d_out, int out_size, void* d_ws,
                              size_t ws_size, hipStream_t stream) {
  const float* x  = (const float*)d_in[0];
  const float* W1 = (const float*)d_in[1];
  const float* b1 = (const float*)d_in[2];
  const float* W2 = (const float*)d_in[3];
  const float* b2 = (const float*)d_in[4];
  const float* Wo = (const float*)d_in[5];
  const float* bo = (const float*)d_in[6];
  const int* nsp  = (const int*)d_in[7];
  float* outp = (float*)d_out;

  float* cur1 = nullptr;
  const size_t need = (size_t)B_TOT * H1 * sizeof(float);
  if (ws_size >= need) {
    cur1 = (float*)d_ws;
    gemm1_kernel<<<B_TOT / 16, 256, 0, stream>>>(x, W1, b1, cur1);
  }

  const size_t ldsB = (size_t)(H1 * H2 + H2 * NC) * sizeof(float);  // 133 KB
  hipFuncSetAttribute((const void*)snn_kernel,
                      hipFuncAttributeMaxDynamicSharedMemorySize, (int)ldsB);
  snn_kernel<<<B_TOT / 16, 1024, ldsB, stream>>>(cur1, x, W1, b1, W2, b2, Wo,
                                                 bo, nsp, outp);
}

// Round 2
// 151.092 us; speedup vs baseline: 1.3372x; 1.3372x over previous
//
#include <hip/hip_runtime.h>
#include <stdint.h>

#define B_TOT 16384
#define IN_DIM 128
#define H1 256
#define H2 128
#define NC 10

// ---------------------------------------------------------------------------
// Kernel A: cur1[b][n] = sum_k x[b][k] * W1[n][k]  (+ b1[n] added at the end)
// ---------------------------------------------------------------------------
__global__ __launch_bounds__(256) void gemm1_kernel(
    const float* __restrict__ x, const float* __restrict__ W1,
    const float* __restrict__ b1, float* __restrict__ cur1) {
  __shared__ float xs[16 * 128];
  const int tid = threadIdx.x;
  const long row0 = (long)blockIdx.x * 16;

  const float4* xt = (const float4*)(x + row0 * IN_DIM);
  float4* xs4 = (float4*)xs;
  xs4[tid] = xt[tid];
  xs4[tid + 256] = xt[tid + 256];
  __syncthreads();

  const int n = tid;
  float acc[16];
#pragma unroll
  for (int r = 0; r < 16; ++r) acc[r] = 0.f;

  const float* wrow = W1 + n * IN_DIM;
  for (int k0 = 0; k0 < IN_DIM; k0 += 4) {
    const float4 wv = *(const float4*)(wrow + k0);
#pragma unroll
    for (int r = 0; r < 16; ++r) {
      const float4 xv = *(const float4*)(xs + r * IN_DIM + k0);
      acc[r] = fmaf(wv.x, xv.x, acc[r]);
      acc[r] = fmaf(wv.y, xv.y, acc[r]);
      acc[r] = fmaf(wv.z, xv.z, acc[r]);
      acc[r] = fmaf(wv.w, xv.w, acc[r]);
    }
  }
  const float bias = b1[n];
#pragma unroll
  for (int r = 0; r < 16; ++r)
    cur1[(row0 + r) * H1 + n] = acc[r] + bias;
}

// ---------------------------------------------------------------------------
// Kernel A2: global transpose of W2 (128x256 -> 256x128) and Wo (10x128 ->
// 128x10) into workspace so the SNN kernel can stage LDS with a straight
// coalesced copy (conflict-free LDS writes).
// ---------------------------------------------------------------------------
__global__ __launch_bounds__(1024) void transpose_kernel(
    const float* __restrict__ W2, const float* __restrict__ Wo,
    float* __restrict__ W2T, float* __restrict__ WoT) {
  const int idx = blockIdx.x * 1024 + threadIdx.x;
  if (idx < H2 * H1) {
    const int o = idx >> 8;   // /256
    const int j = idx & 255;
    W2T[j * H2 + o] = W2[idx];        // coalesced read, scattered write (tiny)
  } else {
    const int k = idx - H2 * H1;
    if (k < NC * H2) {
      const int o = k >> 7;   // /128
      const int j = k & 127;
      WoT[j * NC + o] = Wo[k];
    }
  }
}

// ---------------------------------------------------------------------------
// Kernel B: fused 20-step recurrent SNN. Persistent: 256 blocks (1/CU),
// 16 waves/block, each wave runs 4 batch rows sequentially. W2T/WoT staged
// once per block via conflict-free coalesced float4 copy.
//   lane l owns L1 neurons {l,64+l,128+l,192+l}, L2 neurons {2l,2l+1},
//   lanes 0..9 own the 10 output neurons.
// Sparse current accumulation iterates ballot-mask set bits; summation order
// (group i ascending, j ascending within group) is kept bit-identical to the
// round-1 kernel, which matched the reference exactly.
// ---------------------------------------------------------------------------
__global__ __launch_bounds__(1024) void snn_kernel(
    const float* __restrict__ cur1,
    const float* __restrict__ W2Tg, const float* __restrict__ WoTg,
    const float* __restrict__ W2, const float* __restrict__ Wo,
    const float* __restrict__ x, const float* __restrict__ W1,
    const float* __restrict__ b1,
    const float* __restrict__ b2, const float* __restrict__ bo,
    const int* __restrict__ nsp, float* __restrict__ out) {
  extern __shared__ float lds[];
  float* w2t = lds;             // [in=256][out=128]
  float* wot = lds + H1 * H2;   // [in=128][out=10]

  const int tid = threadIdx.x;
  if (W2Tg != nullptr) {
    // straight copy of pre-transposed weights: conflict-free, coalesced
    float4* dst = (float4*)w2t;
    const float4* src = (const float4*)W2Tg;
#pragma unroll
    for (int i = 0; i < 8; ++i) dst[tid + i * 1024] = src[tid + i * 1024];
    if (tid < (NC * H2) / 4) ((float4*)wot)[tid] = ((const float4*)WoTg)[tid];
  } else {
    // fallback: in-kernel transpose (bank-conflicted but only once per CU)
    for (int idx = tid; idx < H2 * H1; idx += 1024) {
      const int o = idx >> 8;
      const int j = idx & 255;
      w2t[j * H2 + o] = W2[idx];
    }
    for (int idx = tid; idx < NC * H2; idx += 1024) {
      const int o = idx >> 7;
      const int j = idx & 127;
      wot[j * NC + o] = Wo[idx];
    }
  }
  __syncthreads();

  const int w = tid >> 6;
  const int l = tid & 63;
  const int lo = (l < NC) ? l : 0;
  const float bb0 = b2[2 * l];
  const float bb1 = b2[2 * l + 1];
  const float bol = bo[lo];
  const float* w2l = w2t + 2 * l;
  const int nsteps = *nsp;

  for (int r = 0; r < 4; ++r) {
    const long b = (long)blockIdx.x * 64 + w * 4 + r;

    float c[4];
    if (cur1 != nullptr) {
#pragma unroll
      for (int i = 0; i < 4; ++i) c[i] = cur1[b * H1 + i * 64 + l];
    } else {
      const float* xr = x + b * IN_DIM;
#pragma unroll
      for (int i = 0; i < 4; ++i) {
        const int n = i * 64 + l;
        const float* wr = W1 + n * IN_DIM;
        float a = 0.f;
        for (int k = 0; k < IN_DIM; k += 4) {
          const float4 wv = *(const float4*)(wr + k);
          const float4 xv = *(const float4*)(xr + k);
          a = fmaf(wv.x, xv.x, a);
          a = fmaf(wv.y, xv.y, a);
          a = fmaf(wv.z, xv.z, a);
          a = fmaf(wv.w, xv.w, a);
        }
        c[i] = a + b1[n];
      }
    }

    float m1[4] = {0.f, 0.f, 0.f, 0.f};
    float sp1[4] = {0.f, 0.f, 0.f, 0.f};
    float m2a = 0.f, m2b = 0.f, sp2a = 0.f, sp2b = 0.f;
    float mo = 0.f, spo = 0.f, cnt = 0.f;

    for (int t = 0; t < nsteps; ++t) {
      // ---- layer 1 LIF ----
      unsigned long long mk[4];
#pragma unroll
      for (int i = 0; i < 4; ++i) {
        m1[i] = fmaf(0.5f, m1[i], c[i]) - sp1[i];
        const bool s = m1[i] > 1.0f;
        mk[i] = __ballot(s);
        sp1[i] = s ? 1.0f : 0.0f;
      }

      // ---- cur2 = s1 @ W2^T (+ b2): iterate set bits only ----
      float a0 = 0.f, a1 = 0.f;
#pragma unroll
      for (int i = 0; i < 4; ++i) {
        unsigned long long m = mk[i];
        const float* base = w2l + (i * 64) * H2;
        while (m) {
          const int j = __builtin_ctzll(m);
          m &= m - 1;
          const float2 wv = *(const float2*)(base + j * H2);
          a0 += wv.x;
          a1 += wv.y;
        }
      }
      a0 += bb0;
      a1 += bb1;

      // ---- layer 2 LIF ----
      m2a = fmaf(0.5f, m2a, a0) - sp2a;
      m2b = fmaf(0.5f, m2b, a1) - sp2b;
      const bool sa = m2a > 1.0f;
      const bool sb = m2b > 1.0f;
      unsigned long long mA = __ballot(sa);
      unsigned long long mB = __ballot(sb);
      sp2a = sa ? 1.0f : 0.0f;
      sp2b = sb ? 1.0f : 0.0f;

      // ---- output layer ----
      float co = 0.f;
      while (mA) {
        const int j = __builtin_ctzll(mA);
        mA &= mA - 1;
        co += wot[(2 * j) * NC + lo];
      }
      while (mB) {
        const int j = __builtin_ctzll(mB);
        mB &= mB - 1;
        co += wot[(2 * j + 1) * NC + lo];
      }
      co += bol;

      // ---- output LIF + spike count ----
      mo = fmaf(0.5f, mo, co) - spo;
      const bool so = mo > 1.0f;
      spo = so ? 1.0f : 0.0f;
      cnt += spo;
    }

    if (l < NC) out[b * NC + l] = cnt;
  }
}

// ---------------------------------------------------------------------------
extern "C" void kernel_launch(void* const* d_in, const int* in_sizes, int n_in,
                              void* d_out, int out_size, void* d_ws,
                              size_t ws_size, hipStream_t stream) {
  const float* x  = (const float*)d_in[0];
  const float* W1 = (const float*)d_in[1];
  const float* b1 = (const float*)d_in[2];
  const float* W2 = (const float*)d_in[3];
  const float* b2 = (const float*)d_in[4];
  const float* Wo = (const float*)d_in[5];
  const float* bo = (const float*)d_in[6];
  const int* nsp  = (const int*)d_in[7];
  float* outp = (float*)d_out;

  const size_t cur1_bytes = (size_t)B_TOT * H1 * sizeof(float);       // 16 MB
  const size_t w2t_bytes  = (size_t)H1 * H2 * sizeof(float);          // 128 KB
  const size_t wot_bytes  = (size_t)H2 * NC * sizeof(float);          // 5 KB

  float* cur1 = nullptr;
  float* W2Tg = nullptr;
  float* WoTg = nullptr;

  if (ws_size >= cur1_bytes) {
    cur1 = (float*)d_ws;
    gemm1_kernel<<<B_TOT / 16, 256, 0, stream>>>(x, W1, b1, cur1);
  }
  if (ws_size >= cur1_bytes + w2t_bytes + wot_bytes) {
    W2Tg = (float*)((char*)d_ws + cur1_bytes);
    WoTg = W2Tg + H1 * H2;
    transpose_kernel<<<(H2 * H1 + NC * H2 + 1023) / 1024, 1024, 0, stream>>>(
        W2, Wo, W2Tg, WoTg);
  }

  const size_t ldsB = (size_t)(H1 * H2 + H2 * NC) * sizeof(float);  // 133 KB
  hipFuncSetAttribute((const void*)snn_kernel,
                      hipFuncAttributeMaxDynamicSharedMemorySize, (int)ldsB);
  snn_kernel<<<256, 1024, ldsB, stream>>>(cur1, W2Tg, WoTg, W2, Wo, x, W1, b1,
                                          b2, bo, nsp, outp);
}